// Round 5
// baseline (275.117 us; speedup 1.0000x reference)
//
#include <hip/hip_runtime.h>

// ---------------------------------------------------------------------------
// CustomMultiHeadAttentionStoich: fused MHA with RoPE + frac-difference bias.
// B=2 T=2048 D_MODEL=1024 H=16 hd=64. All matmuls via mfma_f32_16x16x32_bf16.
//
// Verified gfx950 fragment layouts (learn_hip m89/m91, rounds 1-4 pass):
//   A-frag : lane holds A[m=lane&15][k=(lane>>4)*8 + j], j=0..7  (8 bf16, 16B)
//   B-frag : lane holds B[k=(lane>>4)*8 + j][n=lane&15]
//   C/D    : lane holds D[row=(lane>>4)*4 + r][col=lane&15], r=0..3 (4 f32)
//
// Round-5 changes:
//  * GEMM cores: single-barrier double-buffered global_load_lds (the k_attn
//    stage() pattern) instead of 2-barrier DMA -- prefetch overlaps MFMA.
//  * k_v_transpose fused into QKV z==2 epilogue (scalar transposed stores).
//  * convert_x + rope_table + transpose_w merged into one k_prep launch.
//  * k_attn: per-g P round-trip interleaves exp-VALU under PV MFMAs; pT 9KB.
//  4 launches total (was 7).
// ---------------------------------------------------------------------------

typedef unsigned short u16;
typedef __bf16 bf8v __attribute__((ext_vector_type(8)));
typedef __bf16 bf4v __attribute__((ext_vector_type(4)));
typedef float f32x4 __attribute__((ext_vector_type(4)));

#define D_MODEL 1024
#define T_SEQ   2048
#define NHEAD   16
#define HDIM    64
#define BATCH   2
#define M_TOT   (BATCH * T_SEQ) /* 4096 */
#define LOG2E   1.4426950408889634f

__device__ __forceinline__ void gl2lds16(const u16* g, u16* l) {
  __builtin_amdgcn_global_load_lds(
      (__attribute__((address_space(1))) void*)g,
      (__attribute__((address_space(3))) void*)l, 16, 0, 0);
}

// ---------------------------------------------------------------------------
// k_prep: zone-partitioned prep work in ONE launch.
//   blocks [0,6144)    : f32->bf16 convert of q/k/v into Xb
//   blocks [6144,7168) : W^T bf16 transpose of Wq/Wk/Wv/Wo into WtB
//   blocks [7168,7424) : RoPE cos/sin table
__global__ __launch_bounds__(256) void k_prep(
    const float* __restrict__ q, const float* __restrict__ k,
    const float* __restrict__ v, const float* __restrict__ Wq,
    const float* __restrict__ Wk, const float* __restrict__ Wv,
    const float* __restrict__ Wo, u16* __restrict__ Xb, u16* __restrict__ WtB,
    float* __restrict__ ct, float* __restrict__ st) {
  __shared__ float tile[64 * 65];
  int bx = blockIdx.x, tid = threadIdx.x;
  if (bx < 6144) { // ---- convert zone
    int z = bx >> 11, xb = bx & 2047;
    const float* src = (z == 0) ? q : (z == 1) ? k : v;
    u16* dst = Xb + (size_t)z * (M_TOT * D_MODEL);
    int idx = (xb * 256 + tid) * 8;
    float4 a = *(const float4*)(src + idx);
    float4 b = *(const float4*)(src + idx + 4);
    bf8v o;
    o[0] = (__bf16)a.x; o[1] = (__bf16)a.y; o[2] = (__bf16)a.z; o[3] = (__bf16)a.w;
    o[4] = (__bf16)b.x; o[5] = (__bf16)b.y; o[6] = (__bf16)b.z; o[7] = (__bf16)b.w;
    *(bf8v*)(dst + idx) = o;
  } else if (bx < 7168) { // ---- W transpose zone (64x64 tiles, stride 65)
    int idx2 = bx - 6144;
    int z = idx2 >> 8, rem = idx2 & 255;
    int k0 = (rem >> 4) * 64, n0 = (rem & 15) * 64;
    const float* W = (z == 0) ? Wq : (z == 1) ? Wk : (z == 2) ? Wv : Wo;
    u16* Wt = WtB + (size_t)z * (D_MODEL * D_MODEL);
#pragma unroll
    for (int i = 0; i < 16; i++) {
      int idx = tid + i * 256;
      int r = idx >> 6, c = idx & 63;
      tile[c * 65 + r] = W[(size_t)(k0 + r) * D_MODEL + n0 + c];
    }
    __syncthreads();
#pragma unroll
    for (int i = 0; i < 16; i++) {
      int idx = tid + i * 256;
      int r = idx >> 6, c = idx & 63;
      ((__bf16*)Wt)[(size_t)(n0 + r) * D_MODEL + k0 + c] = (__bf16)tile[r * 65 + c];
    }
  } else { // ---- RoPE table zone: angle(t,d) = t / 10000^(d/32)
    int idx = (bx - 7168) * 256 + tid; // = t*32 + d
    int t = idx >> 5, d = idx & 31;
    float ang = (float)t * powf(10000.0f, -(float)d * (1.0f / 32.0f));
    ct[idx] = cosf(ang);
    st[idx] = sinf(ang);
  }
}

// ---------------------------------------------------------------------------
// Tiled GEMM core: C = A[M][K] @ Bt[N][K]^T, K=1024, BK=32.
// Single-barrier double-buffered global_load_lds staging (k_attn pattern):
// stage(buf^1) issues before compute of buf; barrier at loop end drains
// own-wave DMA (vmcnt) and orders buffer reuse. BM=128; BN in {64,128}.
// sA = [2][128*32], sB = [2][BN*32].
template <int BN>
__device__ __forceinline__ void gemm_core_db(const u16* __restrict__ A,
                                             const u16* __restrict__ Bt,
                                             u16* sA, u16* sB,
                                             f32x4 (&acc)[4][BN / 32],
                                             int m0, int n0) {
  const int K = D_MODEL;
  int tid = threadIdx.x;
  int lane = tid & 63, wave = tid >> 6;
  int l15 = lane & 15, quad = lane >> 4;
  int wm = (wave >> 1) * 64, wn = (wave & 1) * (BN / 2);
  int arow = tid >> 2, acol = (tid & 3) * 8; // lane deposit: row tid>>2, col (tid&3)*8
  const u16* Ap0 = A + (size_t)(m0 + arow) * K + acol;
  const u16* Ap1 = Ap0 + (size_t)64 * K;
  const u16* Bp0 = Bt + (size_t)(n0 + arow) * K + acol;
  const u16* Bp1 = Bp0 + (size_t)64 * K; // used only when BN==128
  u16* dA0 = sA + wave * 512; // wave-uniform LDS bases (lane -> +lane*16B)
  u16* dA1 = sA + 2048 + wave * 512;
  u16* dB0 = sB + wave * 512;
  u16* dB1 = sB + 2048 + wave * 512;

  auto stage = [&](int buf, int k0) {
    int oa = buf * (128 * 32);
    int ob = buf * (BN * 32);
    gl2lds16(Ap0 + k0, dA0 + oa);
    gl2lds16(Ap1 + k0, dA1 + oa);
    gl2lds16(Bp0 + k0, dB0 + ob);
    if (BN == 128) gl2lds16(Bp1 + k0, dB1 + ob);
  };

  stage(0, 0);
  __syncthreads();
  for (int k0 = 0; k0 < K; k0 += 32) {
    int buf = (k0 >> 5) & 1;
    if (k0 + 32 < K) stage(buf ^ 1, k0 + 32); // prefetch overlaps MFMA below
    const u16* bA = sA + buf * (128 * 32);
    const u16* bB = sB + buf * (BN * 32);
    bf8v af[4], bf[BN / 32];
#pragma unroll
    for (int i = 0; i < 4; i++)
      af[i] = *(const bf8v*)(bA + (wm + i * 16 + l15) * 32 + quad * 8);
#pragma unroll
    for (int i = 0; i < BN / 32; i++)
      bf[i] = *(const bf8v*)(bB + (wn + i * 16 + l15) * 32 + quad * 8);
#pragma unroll
    for (int mi = 0; mi < 4; mi++)
#pragma unroll
      for (int ni = 0; ni < BN / 32; ni++)
        acc[mi][ni] = __builtin_amdgcn_mfma_f32_16x16x32_bf16(
            af[mi], bf[ni], acc[mi][ni], 0, 0, 0);
    __syncthreads(); // drains own DMA (vmcnt) + all waves done with buf
  }
}

// QKV projection, grid (8, 32, 3). z<2 -> RoPE fused; z==0 prescales Q by
// 0.125*log2e. z==2 writes projected V DIRECTLY TRANSPOSED into Vb[b][h][d][t]
// (fuses the old k_v_transpose; scalar stores, L2 write-combines).
__global__ __launch_bounds__(256) void k_gemm_qkv(
    const u16* __restrict__ Xb, const u16* __restrict__ WtB,
    const float* __restrict__ bq, const float* __restrict__ bk,
    const float* __restrict__ bv, const float* __restrict__ ctab,
    const float* __restrict__ stab, u16* __restrict__ OutB,
    u16* __restrict__ Vb) {
  __shared__ __align__(16) u16 sA[2][128 * 32];
  __shared__ __align__(16) u16 sB[2][128 * 32];
  int z = blockIdx.z;
  const u16* A = Xb + (size_t)z * (M_TOT * D_MODEL);
  const u16* Bt = WtB + (size_t)z * (D_MODEL * D_MODEL);
  const float* bias = (z == 0) ? bq : (z == 1) ? bk : bv;
  u16* Out = OutB + (size_t)z * (M_TOT * D_MODEL);
  int m0 = blockIdx.y * 128, n0 = blockIdx.x * 128;
  f32x4 acc[4][4] = {};
  gemm_core_db<128>(A, Bt, &sA[0][0], &sB[0][0], acc, m0, n0);

  int tid = threadIdx.x, lane = tid & 63, wave = tid >> 6;
  int l15 = lane & 15, quad = lane >> 4;
  int wm = (wave >> 1) * 64, wn = (wave & 1) * 64;
  float bvv[4];
#pragma unroll
  for (int ni = 0; ni < 4; ni++) bvv[ni] = bias[n0 + wn + ni * 16 + l15];

  if (z < 2) { // Q/K: RoPE fused; Q also prescaled 0.125*log2e
    float qs = (z == 0) ? 0.125f * LOG2E : 1.0f;
#pragma unroll
    for (int mi = 0; mi < 4; mi++) {
#pragma unroll
      for (int r = 0; r < 4; r++) {
        int m = m0 + wm + mi * 16 + quad * 4 + r; // global row = b*T + t
        size_t ro = (size_t)m * D_MODEL + n0 + wn;
        int tl = m & (T_SEQ - 1);
#pragma unroll
        for (int ni = 0; ni < 2; ni++) {
          int d = ni * 16 + l15; // < 32; pair (d, d+32) in regs ni, ni+2
          float c = ctab[tl * 32 + d], s = stab[tl * 32 + d];
          float xl = acc[mi][ni][r] + bvv[ni];
          float xr = acc[mi][ni + 2][r] + bvv[ni + 2];
          ((__bf16*)Out)[ro + d] = (__bf16)((xl * c - xr * s) * qs);
          ((__bf16*)Out)[ro + d + 32] = (__bf16)((xl * s + xr * c) * qs);
        }
      }
    }
  } else { // V: write transposed Vb[b][h][d][t] (wave's 64 cols = one head)
    int hh = (n0 + wn) >> 6;
    int mbase = m0 + wm;
    int bb = mbase >> 11;      // tile never crosses batch (2048 % 128 == 0)
    int tbase = mbase & (T_SEQ - 1);
    u16* Vw = Vb + (size_t)(bb * NHEAD + hh) * HDIM * T_SEQ;
#pragma unroll
    for (int mi = 0; mi < 4; mi++)
#pragma unroll
      for (int r = 0; r < 4; r++) {
        int t = tbase + mi * 16 + quad * 4 + r;
#pragma unroll
        for (int ni = 0; ni < 4; ni++) {
          int d = ni * 16 + l15;
          ((__bf16*)Vw)[(size_t)d * T_SEQ + t] = (__bf16)(acc[mi][ni][r] + bvv[ni]);
        }
      }
  }
}

// Output projection: ctx bf16 @ Wo^T + bo -> f32 d_out. 128x64 tiles,
// grid (16, 32) = 512 blocks (2/CU).
__global__ __launch_bounds__(256) void k_gemm_out(
    const u16* __restrict__ ctx, const u16* __restrict__ Wot,
    const float* __restrict__ bo, float* __restrict__ Cout) {
  __shared__ __align__(16) u16 sA[2][128 * 32];
  __shared__ __align__(16) u16 sB[2][64 * 32];
  int m0 = blockIdx.y * 128, n0 = blockIdx.x * 64;
  f32x4 acc[4][2] = {};
  gemm_core_db<64>(ctx, Wot, &sA[0][0], &sB[0][0], acc, m0, n0);
  int tid = threadIdx.x, lane = tid & 63, wave = tid >> 6;
  int l15 = lane & 15, quad = lane >> 4;
  int wm = (wave >> 1) * 64, wn = (wave & 1) * 32;
  float bvv[2];
#pragma unroll
  for (int ni = 0; ni < 2; ni++) bvv[ni] = bo[n0 + wn + ni * 16 + l15];
#pragma unroll
  for (int mi = 0; mi < 4; mi++)
#pragma unroll
    for (int r = 0; r < 4; r++) {
      size_t ro = (size_t)(m0 + wm + mi * 16 + quad * 4 + r) * D_MODEL + n0 + wn;
#pragma unroll
      for (int ni = 0; ni < 2; ni++)
        Cout[ro + ni * 16 + l15] = acc[mi][ni][r] + bvv[ni];
    }
}

// ---------------------------------------------------------------------------
// Flash attention v5: grid (T/128, B*H), 256 thr (4 waves x 32q). K/V tiles
// double-buffered in LDS via global_load_lds DMA; ONE __syncthreads per tile.
// XOR-chunk swizzle (pc = gc ^ (row&7)): lane-linear DMA deposit AND
// conflict-free b128 frag reads. S^T = K@Q^T -> per-lane softmax, no
// max-subtraction, exp2-native. Per-g P round-trip: g1's exp VALU issues
// under g0's PV MFMAs.
__global__ __launch_bounds__(256) void k_attn(
    const u16* __restrict__ Qr, const u16* __restrict__ Kr,
    const u16* __restrict__ Vb, const float* __restrict__ frac,
    const float* __restrict__ alpha_pos, const float* __restrict__ alpha_neg,
    u16* __restrict__ ctx) {
  __shared__ __align__(16) u16 kT[2][64 * 64]; // swizzled [key][d], no pad
  __shared__ __align__(16) u16 vT[2][64 * 64]; // swizzled [d][key], no pad
  __shared__ __align__(16) u16 pT[4][16 * 72]; // per-wave [q][key], one g
  int bh = blockIdx.y, b = bh >> 4, h = bh & 15;
  int q0 = blockIdx.x * 128;
  int tid = threadIdx.x, wave = tid >> 6, lane = tid & 63;
  int l15 = lane & 15, quad = lane >> 4;

  const u16* Kh = Kr + (size_t)b * T_SEQ * D_MODEL + h * HDIM;
  const u16* Vh = Vb + (size_t)bh * HDIM * T_SEQ;
  const float* fb = frac + b * T_SEQ;

  // Q B-frags (B[k=d][n=q] = Q[q][d]): lane holds Q[q=l15][d=quad*8+j]
  bf8v qf[2][2];
  float fq[2];
#pragma unroll
  for (int g = 0; g < 2; g++) {
    int qrow = q0 + wave * 32 + g * 16 + l15;
    const u16* qbase =
        Qr + (size_t)(b * T_SEQ + qrow) * D_MODEL + h * HDIM + quad * 8;
    qf[g][0] = *(const bf8v*)qbase;
    qf[g][1] = *(const bf8v*)(qbase + 32);
    fq[g] = fb[qrow]; // S^T col = q = l15
  }
  float ap = alpha_pos[h] * LOG2E, an = alpha_neg[h] * LOG2E;
  bf8v onesv;
#pragma unroll
  for (int j = 0; j < 8; j++) onesv[j] = (__bf16)1.0f;
  f32x4 o[2][4] = {};
  f32x4 o_l[2] = {};
  u16* pw = (u16*)pT[wave];

  // DMA staging map: call j, wave w, lane l -> physical chunk p=j*256+w*64+l;
  // row = p>>3, pc = p&7; fetch global chunk gc = pc ^ (row&7).
  int p0 = tid, p1 = 256 + tid;
  int kr0 = p0 >> 3, gc0 = (p0 & 7) ^ (kr0 & 7);
  int kr1 = p1 >> 3, gc1 = (p1 & 7) ^ (kr1 & 7);
  const u16* kg0 = Kh + (size_t)kr0 * D_MODEL + gc0 * 8;
  const u16* kg1 = Kh + (size_t)kr1 * D_MODEL + gc1 * 8;
  const u16* vg0 = Vh + (size_t)kr0 * T_SEQ + gc0 * 8; // row = d here
  const u16* vg1 = Vh + (size_t)kr1 * T_SEQ + gc1 * 8;
  int woff = wave * 512; // wave-uniform LDS dest (elems); lane -> +lane*8

  auto stage = [&](int buf, int kbase) {
    gl2lds16(kg0 + (size_t)kbase * D_MODEL, kT[buf] + woff);
    gl2lds16(kg1 + (size_t)kbase * D_MODEL, kT[buf] + 2048 + woff);
    gl2lds16(vg0 + kbase, vT[buf] + woff);
    gl2lds16(vg1 + kbase, vT[buf] + 2048 + woff);
  };

  stage(0, 0);
  __syncthreads();

  for (int kt = 0; kt < T_SEQ / 64; kt++) {
    int kbase = kt * 64;
    int buf = kt & 1;
    if (kt + 1 < T_SEQ / 64) stage(buf ^ 1, kbase + 64);

    // K A-frags via swizzle: row k = nt*16+l15; chunk gc -> pc = gc^(k&7)
    bf8v kf0[4], kf1[4];
    int x0 = (quad ^ (l15 & 7)) * 8; // pc for gc=quad; gc=quad+4 -> ^32 elems
#pragma unroll
    for (int nt = 0; nt < 4; nt++) {
      const u16* rb = kT[buf] + ((nt * 16 + l15) << 6);
      kf0[nt] = *(const bf8v*)(rb + x0);
      kf1[nt] = *(const bf8v*)(rb + (x0 ^ 32));
    }
    // V B-frags: row d = dt*16+l15; key-chunks gc = kc*4+quad
    bf8v vf[2][4];
#pragma unroll
    for (int dt = 0; dt < 4; dt++) {
      const u16* rb = vT[buf] + ((dt * 16 + l15) << 6);
      vf[0][dt] = *(const bf8v*)(rb + x0);
      vf[1][dt] = *(const bf8v*)(rb + (x0 ^ 32));
    }
    f32x4 fk4[4];
#pragma unroll
    for (int nt = 0; nt < 4; nt++)
      fk4[nt] = *(const f32x4*)(fb + kbase + nt * 16 + quad * 4);

#pragma unroll
    for (int g = 0; g < 2; g++) {
      float fqg = fq[g];
#pragma unroll
      for (int nt = 0; nt < 4; nt++) {
        // S^T tile: D[row=key=nt*16+quad*4+r][col=q=l15], log2 domain
        f32x4 s = {};
        s = __builtin_amdgcn_mfma_f32_16x16x32_bf16(kf0[nt], qf[g][0], s, 0, 0, 0);
        s = __builtin_amdgcn_mfma_f32_16x16x32_bf16(kf1[nt], qf[g][1], s, 0, 0, 0);
        bf4v pk;
#pragma unroll
        for (int r = 0; r < 4; r++) {
          float dd = fk4[nt][r] - fqg;
          float sel = (dd >= 0.0f) ? ap : an;
          float p = __builtin_amdgcn_exp2f(fmaf(dd, sel, s[r]));
          pk[r] = (__bf16)p;
        }
        // P[q=l15][key = nt*16 + quad*4 + r] -> one b64 write
        *(bf4v*)(pw + l15 * 72 + nt * 16 + quad * 4) = pk;
      }
      asm volatile("s_waitcnt lgkmcnt(0)" ::: "memory"); // P visible to own wave
      // O_g += P_g @ V ; l_g += P_g @ ones. These MFMAs drain while the
      // next g's score VALU issues (separate pipes, same wave).
#pragma unroll
      for (int kc = 0; kc < 2; kc++) {
        bf8v pf = *(const bf8v*)(pw + l15 * 72 + kc * 32 + quad * 8);
        o_l[g] = __builtin_amdgcn_mfma_f32_16x16x32_bf16(pf, onesv, o_l[g], 0, 0, 0);
#pragma unroll
        for (int dt = 0; dt < 4; dt++)
          o[g][dt] = __builtin_amdgcn_mfma_f32_16x16x32_bf16(pf, vf[kc][dt],
                                                             o[g][dt], 0, 0, 0);
      }
    }
    __syncthreads(); // drains this iter's DMA (vmcnt) + frees cur buf
  }

  // epilogue: l sits in o_l C-layout rows (same rows as o)
#pragma unroll
  for (int g = 0; g < 2; g++) {
#pragma unroll
    for (int r = 0; r < 4; r++) {
      float linv = 1.0f / o_l[g][r];
      int qg = q0 + wave * 32 + g * 16 + quad * 4 + r;
      __bf16* orow = (__bf16*)(ctx + (size_t)(b * T_SEQ + qg) * D_MODEL + h * HDIM);
#pragma unroll
      for (int dt = 0; dt < 4; dt++)
        orow[dt * 16 + l15] = (__bf16)(o[g][dt][r] * linv);
    }
  }
}

// ---------------------------------------------------------------------------
extern "C" void kernel_launch(void* const* d_in, const int* in_sizes, int n_in,
                              void* d_out, int out_size, void* d_ws,
                              size_t ws_size, hipStream_t stream) {
  const float* q = (const float*)d_in[0];
  const float* k = (const float*)d_in[1];
  const float* v = (const float*)d_in[2];
  const float* frac = (const float*)d_in[3];
  const float* Wq = (const float*)d_in[4];
  const float* Wk = (const float*)d_in[5];
  const float* Wv = (const float*)d_in[6];
  const float* Wo = (const float*)d_in[7];
  const float* bq = (const float*)d_in[8];
  const float* bk = (const float*)d_in[9];
  const float* bv = (const float*)d_in[10];
  const float* bo = (const float*)d_in[11];
  const float* alpha_pos = (const float*)d_in[12];
  const float* alpha_neg = (const float*)d_in[13];

  char* ws = (char*)d_ws;
  u16* Xb = (u16*)(ws + 0);
  u16* Wt = (u16*)(ws + 25165824);
  u16* Qr = (u16*)(ws + 33554432);
  u16* Kr = (u16*)(ws + 41943040);
  u16* Vtmp = (u16*)(ws + 50331648); // unused as V now; holds ctx
  u16* Vb = (u16*)(ws + 58720256);
  float* ctab = (float*)(ws + 67108864);
  float* stab = (float*)(ws + 67371008);
  u16* ctx = Vtmp;
  u16* QKVout = Qr; // Qr,Kr contiguous; z==2 writes Vb directly

  k_prep<<<dim3(7424), 256, 0, stream>>>(q, k, v, Wq, Wk, Wv, Wo, Xb, Wt, ctab,
                                         stab);
  k_gemm_qkv<<<dim3(8, 32, 3), 256, 0, stream>>>(Xb, Wt, bq, bk, bv, ctab, stab,
                                                 QKVout, Vb);
  k_attn<<<dim3(16, 32), 256, 0, stream>>>(Qr, Kr, Vb, frac, alpha_pos,
                                           alpha_neg, ctx);
  k_gemm_out<<<dim3(16, 32), 256, 0, stream>>>(ctx, Wt + 3 * 1048576, bo,
                                               (float*)d_out);
}

// Round 6
// 256.860 us; speedup vs baseline: 1.0711x; 1.0711x over previous
//
#include <hip/hip_runtime.h>

// ---------------------------------------------------------------------------
// CustomMultiHeadAttentionStoich: fused MHA with RoPE + frac-difference bias.
// B=2 T=2048 D_MODEL=1024 H=16 hd=64. All matmuls via mfma_f32_16x16x32_bf16.
//
// Verified gfx950 fragment layouts (learn_hip m89/m91, rounds 1-5 pass):
//   A-frag : lane holds A[m=lane&15][k=(lane>>4)*8 + j], j=0..7  (8 bf16, 16B)
//   B-frag : lane holds B[k=(lane>>4)*8 + j][n=lane&15]
//   C/D    : lane holds D[row=(lane>>4)*4 + r][col=lane&15], r=0..3 (4 f32)
//
// Round-6 changes:
//  * GEMM core: REVERT to r4 BK=64 2-barrier single-buffer (r5's
//    single-barrier db regressed: BK=32 compute << DMA latency, barrier
//    drained its own prefetch 32x/loop). r5 fusions kept.
//  * k_attn: hoisted LDS frag offsets; bias term precomputed per-tile as
//    f32x4 vector math; pT[wave][2] restored -> ONE lgkmcnt drain per kt
//    (S-MFMA+exp+P-write for both g, drain, PV for both g).
// ---------------------------------------------------------------------------

typedef unsigned short u16;
typedef __bf16 bf8v __attribute__((ext_vector_type(8)));
typedef __bf16 bf4v __attribute__((ext_vector_type(4)));
typedef float f32x4 __attribute__((ext_vector_type(4)));

#define D_MODEL 1024
#define T_SEQ   2048
#define NHEAD   16
#define HDIM    64
#define BATCH   2
#define M_TOT   (BATCH * T_SEQ) /* 4096 */
#define LOG2E   1.4426950408889634f

__device__ __forceinline__ void gl2lds16(const u16* g, u16* l) {
  __builtin_amdgcn_global_load_lds(
      (__attribute__((address_space(1))) void*)g,
      (__attribute__((address_space(3))) void*)l, 16, 0, 0);
}

// ---------------------------------------------------------------------------
// k_prep: zone-partitioned prep work in ONE launch.
//   blocks [0,6144)    : f32->bf16 convert of q/k/v into Xb
//   blocks [6144,7168) : W^T bf16 transpose of Wq/Wk/Wv/Wo into WtB
//   blocks [7168,7424) : RoPE cos/sin table
__global__ __launch_bounds__(256) void k_prep(
    const float* __restrict__ q, const float* __restrict__ k,
    const float* __restrict__ v, const float* __restrict__ Wq,
    const float* __restrict__ Wk, const float* __restrict__ Wv,
    const float* __restrict__ Wo, u16* __restrict__ Xb, u16* __restrict__ WtB,
    float* __restrict__ ct, float* __restrict__ st) {
  __shared__ float tile[64 * 65];
  int bx = blockIdx.x, tid = threadIdx.x;
  if (bx < 6144) { // ---- convert zone
    int z = bx >> 11, xb = bx & 2047;
    const float* src = (z == 0) ? q : (z == 1) ? k : v;
    u16* dst = Xb + (size_t)z * (M_TOT * D_MODEL);
    int idx = (xb * 256 + tid) * 8;
    float4 a = *(const float4*)(src + idx);
    float4 b = *(const float4*)(src + idx + 4);
    bf8v o;
    o[0] = (__bf16)a.x; o[1] = (__bf16)a.y; o[2] = (__bf16)a.z; o[3] = (__bf16)a.w;
    o[4] = (__bf16)b.x; o[5] = (__bf16)b.y; o[6] = (__bf16)b.z; o[7] = (__bf16)b.w;
    *(bf8v*)(dst + idx) = o;
  } else if (bx < 7168) { // ---- W transpose zone (64x64 tiles, stride 65)
    int idx2 = bx - 6144;
    int z = idx2 >> 8, rem = idx2 & 255;
    int k0 = (rem >> 4) * 64, n0 = (rem & 15) * 64;
    const float* W = (z == 0) ? Wq : (z == 1) ? Wk : (z == 2) ? Wv : Wo;
    u16* Wt = WtB + (size_t)z * (D_MODEL * D_MODEL);
#pragma unroll
    for (int i = 0; i < 16; i++) {
      int idx = tid + i * 256;
      int r = idx >> 6, c = idx & 63;
      tile[c * 65 + r] = W[(size_t)(k0 + r) * D_MODEL + n0 + c];
    }
    __syncthreads();
#pragma unroll
    for (int i = 0; i < 16; i++) {
      int idx = tid + i * 256;
      int r = idx >> 6, c = idx & 63;
      ((__bf16*)Wt)[(size_t)(n0 + r) * D_MODEL + k0 + c] = (__bf16)tile[r * 65 + c];
    }
  } else { // ---- RoPE table zone: angle(t,d) = t / 10000^(d/32)
    int idx = (bx - 7168) * 256 + tid; // = t*32 + d
    int t = idx >> 5, d = idx & 31;
    float ang = (float)t * powf(10000.0f, -(float)d * (1.0f / 32.0f));
    ct[idx] = cosf(ang);
    st[idx] = sinf(ang);
  }
}

// ---------------------------------------------------------------------------
// Tiled GEMM core (r4 structure): C = A[M][K] @ Bt[N][K]^T, K=1024, BK=64
// (two stride-32 planes per operand, bank-balanced b128 frag reads).
// 2-barrier single-buffer global_load_lds staging. BM=128; BN in {64,128}.
template <int BN>
__device__ __forceinline__ void gemm_core_t(const u16* __restrict__ A,
                                            const u16* __restrict__ Bt,
                                            u16* sA, u16* sB,
                                            f32x4 (&acc)[4][BN / 32],
                                            int m0, int n0) {
  const int K = D_MODEL;
  const int PB = BN * 32; // sB plane size (elems)
  int tid = threadIdx.x;
  int lane = tid & 63, wave = tid >> 6;
  int l15 = lane & 15, quad = lane >> 4;
  int wm = (wave >> 1) * 64, wn = (wave & 1) * (BN / 2);
  int r0 = tid >> 2, pcol0 = (tid & 3) * 8;
  int r1 = 64 + r0;
  const u16* A0 = A + (size_t)(m0 + r0) * K + pcol0;
  const u16* A1 = A + (size_t)(m0 + r1) * K + pcol0;
  const u16* B0 = Bt + (size_t)(n0 + r0) * K + pcol0;
  const u16* B1 = Bt + (size_t)(n0 + r1) * K + pcol0;
  u16* dA0 = sA + wave * 512;        // plane0, rows 0..63 (wave-uniform base)
  u16* dA1 = sA + 2048 + wave * 512; // plane0, rows 64..127
  u16* dB0 = sB + wave * 512;
  u16* dB1 = sB + 2048 + wave * 512;
  for (int k0 = 0; k0 < K; k0 += 64) {
    __syncthreads(); // previous iter's frag reads done
    gl2lds16(A0 + k0, dA0);
    gl2lds16(A1 + k0, dA1);
    gl2lds16(A0 + k0 + 32, dA0 + 4096); // plane1
    gl2lds16(A1 + k0 + 32, dA1 + 4096);
    gl2lds16(B0 + k0, dB0);
    gl2lds16(B0 + k0 + 32, dB0 + PB);
    if (BN == 128) {
      gl2lds16(B1 + k0, dB1);
      gl2lds16(B1 + k0 + 32, dB1 + PB);
    }
    __syncthreads(); // barrier drain -> LDS data visible
#pragma unroll
    for (int kh = 0; kh < 2; kh++) {
      bf8v af[4], bf[BN / 32];
#pragma unroll
      for (int i = 0; i < 4; i++)
        af[i] = *(const bf8v*)(sA + kh * 4096 + (wm + i * 16 + l15) * 32 + quad * 8);
#pragma unroll
      for (int i = 0; i < BN / 32; i++)
        bf[i] = *(const bf8v*)(sB + kh * PB + (wn + i * 16 + l15) * 32 + quad * 8);
#pragma unroll
      for (int mi = 0; mi < 4; mi++)
#pragma unroll
        for (int ni = 0; ni < BN / 32; ni++)
          acc[mi][ni] = __builtin_amdgcn_mfma_f32_16x16x32_bf16(
              af[mi], bf[ni], acc[mi][ni], 0, 0, 0);
    }
  }
}

// QKV projection, grid (8, 32, 3). z<2 -> RoPE fused; z==0 prescales Q by
// 0.125*log2e. z==2 writes projected V DIRECTLY TRANSPOSED into Vb[b][h][d][t].
__global__ __launch_bounds__(256) void k_gemm_qkv(
    const u16* __restrict__ Xb, const u16* __restrict__ WtB,
    const float* __restrict__ bq, const float* __restrict__ bk,
    const float* __restrict__ bv, const float* __restrict__ ctab,
    const float* __restrict__ stab, u16* __restrict__ OutB,
    u16* __restrict__ Vb) {
  __shared__ __align__(16) u16 sA[128 * 64];
  __shared__ __align__(16) u16 sB[128 * 64];
  int z = blockIdx.z;
  const u16* A = Xb + (size_t)z * (M_TOT * D_MODEL);
  const u16* Bt = WtB + (size_t)z * (D_MODEL * D_MODEL);
  const float* bias = (z == 0) ? bq : (z == 1) ? bk : bv;
  u16* Out = OutB + (size_t)z * (M_TOT * D_MODEL);
  int m0 = blockIdx.y * 128, n0 = blockIdx.x * 128;
  f32x4 acc[4][4] = {};
  gemm_core_t<128>(A, Bt, sA, sB, acc, m0, n0);

  int tid = threadIdx.x, lane = tid & 63, wave = tid >> 6;
  int l15 = lane & 15, quad = lane >> 4;
  int wm = (wave >> 1) * 64, wn = (wave & 1) * 64;
  float bvv[4];
#pragma unroll
  for (int ni = 0; ni < 4; ni++) bvv[ni] = bias[n0 + wn + ni * 16 + l15];

  if (z < 2) { // Q/K: RoPE fused; Q also prescaled 0.125*log2e
    float qs = (z == 0) ? 0.125f * LOG2E : 1.0f;
#pragma unroll
    for (int mi = 0; mi < 4; mi++) {
#pragma unroll
      for (int r = 0; r < 4; r++) {
        int m = m0 + wm + mi * 16 + quad * 4 + r; // global row = b*T + t
        size_t ro = (size_t)m * D_MODEL + n0 + wn;
        int tl = m & (T_SEQ - 1);
#pragma unroll
        for (int ni = 0; ni < 2; ni++) {
          int d = ni * 16 + l15; // < 32; pair (d, d+32) in regs ni, ni+2
          float c = ctab[tl * 32 + d], s = stab[tl * 32 + d];
          float xl = acc[mi][ni][r] + bvv[ni];
          float xr = acc[mi][ni + 2][r] + bvv[ni + 2];
          ((__bf16*)Out)[ro + d] = (__bf16)((xl * c - xr * s) * qs);
          ((__bf16*)Out)[ro + d + 32] = (__bf16)((xl * s + xr * c) * qs);
        }
      }
    }
  } else { // V: write transposed Vb[b][h][d][t] (wave's 64 cols = one head)
    int hh = (n0 + wn) >> 6;
    int mbase = m0 + wm;
    int bb = mbase >> 11; // tile never crosses batch (2048 % 128 == 0)
    int tbase = mbase & (T_SEQ - 1);
    u16* Vw = Vb + (size_t)(bb * NHEAD + hh) * HDIM * T_SEQ;
#pragma unroll
    for (int mi = 0; mi < 4; mi++)
#pragma unroll
      for (int r = 0; r < 4; r++) {
        int t = tbase + mi * 16 + quad * 4 + r;
#pragma unroll
        for (int ni = 0; ni < 4; ni++) {
          int d = ni * 16 + l15;
          ((__bf16*)Vw)[(size_t)d * T_SEQ + t] = (__bf16)(acc[mi][ni][r] + bvv[ni]);
        }
      }
  }
}

// Output projection: ctx bf16 @ Wo^T + bo -> f32 d_out. 128x64 tiles,
// grid (16, 32) = 512 blocks (2/CU).
__global__ __launch_bounds__(256) void k_gemm_out(
    const u16* __restrict__ ctx, const u16* __restrict__ Wot,
    const float* __restrict__ bo, float* __restrict__ Cout) {
  __shared__ __align__(16) u16 sA[128 * 64];
  __shared__ __align__(16) u16 sB[64 * 64];
  int m0 = blockIdx.y * 128, n0 = blockIdx.x * 64;
  f32x4 acc[4][2] = {};
  gemm_core_t<64>(ctx, Wot, sA, sB, acc, m0, n0);
  int tid = threadIdx.x, lane = tid & 63, wave = tid >> 6;
  int l15 = lane & 15, quad = lane >> 4;
  int wm = (wave >> 1) * 64, wn = (wave & 1) * 32;
  float bvv[2];
#pragma unroll
  for (int ni = 0; ni < 2; ni++) bvv[ni] = bo[n0 + wn + ni * 16 + l15];
#pragma unroll
  for (int mi = 0; mi < 4; mi++)
#pragma unroll
    for (int r = 0; r < 4; r++) {
      size_t ro = (size_t)(m0 + wm + mi * 16 + quad * 4 + r) * D_MODEL + n0 + wn;
#pragma unroll
      for (int ni = 0; ni < 2; ni++)
        Cout[ro + ni * 16 + l15] = acc[mi][ni][r] + bvv[ni];
    }
}

// ---------------------------------------------------------------------------
// Flash attention v6: grid (T/128, B*H), 256 thr (4 waves x 32q). K/V tiles
// double-buffered in LDS via global_load_lds DMA; ONE __syncthreads per tile.
// XOR-chunk swizzle (pc = gc ^ (row&7)). S^T = K@Q^T -> per-lane softmax, no
// max-subtraction, exp2-native. Per kt: S-MFMA + bias/exp + P-write for BOTH
// g, single lgkm drain, then PV-MFMA for both g. Frag offsets hoisted.
__global__ __launch_bounds__(256) void k_attn(
    const u16* __restrict__ Qr, const u16* __restrict__ Kr,
    const u16* __restrict__ Vb, const float* __restrict__ frac,
    const float* __restrict__ alpha_pos, const float* __restrict__ alpha_neg,
    u16* __restrict__ ctx) {
  __shared__ __align__(16) u16 kT[2][64 * 64]; // swizzled [key][d], no pad
  __shared__ __align__(16) u16 vT[2][64 * 64]; // swizzled [d][key], no pad
  __shared__ __align__(16) u16 pT[4][2][16 * 72]; // per-wave per-g [q][key]
  int bh = blockIdx.y, b = bh >> 4, h = bh & 15;
  int q0 = blockIdx.x * 128;
  int tid = threadIdx.x, wave = tid >> 6, lane = tid & 63;
  int l15 = lane & 15, quad = lane >> 4;

  const u16* Kh = Kr + (size_t)b * T_SEQ * D_MODEL + h * HDIM;
  const u16* Vh = Vb + (size_t)bh * HDIM * T_SEQ;
  const float* fb = frac + b * T_SEQ;

  // Q B-frags (B[k=d][n=q] = Q[q][d]): lane holds Q[q=l15][d=quad*8+j]
  bf8v qf[2][2];
  float fq[2];
#pragma unroll
  for (int g = 0; g < 2; g++) {
    int qrow = q0 + wave * 32 + g * 16 + l15;
    const u16* qbase =
        Qr + (size_t)(b * T_SEQ + qrow) * D_MODEL + h * HDIM + quad * 8;
    qf[g][0] = *(const bf8v*)qbase;
    qf[g][1] = *(const bf8v*)(qbase + 32);
    fq[g] = fb[qrow]; // S^T col = q = l15
  }
  float ap = alpha_pos[h] * LOG2E, an = alpha_neg[h] * LOG2E;
  bf8v onesv;
#pragma unroll
  for (int j = 0; j < 8; j++) onesv[j] = (__bf16)1.0f;
  f32x4 o[2][4] = {};
  f32x4 o_l[2] = {};
  u16* pw = &pT[wave][0][0];

  // Hoisted frag offsets (elems). Swizzle: row k, chunk gc -> pc = gc^(k&7).
  int x0 = (quad ^ (l15 & 7)) * 8; // pc offset for gc=quad; gc+4 -> ^32 elems
  int kidx[4], vidx[4], pidx;
#pragma unroll
  for (int nt = 0; nt < 4; nt++) kidx[nt] = ((nt * 16 + l15) << 6) + x0;
#pragma unroll
  for (int dt = 0; dt < 4; dt++) vidx[dt] = ((dt * 16 + l15) << 6) + x0;
  pidx = l15 * 72 + quad * 8;

  // DMA staging map: physical chunk p = j*256 + wave*64 + lane;
  // row = p>>3, pc = p&7; fetch global chunk gc = pc ^ (row&7).
  int p0 = tid, p1 = 256 + tid;
  int kr0 = p0 >> 3, gc0 = (p0 & 7) ^ (kr0 & 7);
  int kr1 = p1 >> 3, gc1 = (p1 & 7) ^ (kr1 & 7);
  const u16* kg0 = Kh + (size_t)kr0 * D_MODEL + gc0 * 8;
  const u16* kg1 = Kh + (size_t)kr1 * D_MODEL + gc1 * 8;
  const u16* vg0 = Vh + (size_t)kr0 * T_SEQ + gc0 * 8; // row = d here
  const u16* vg1 = Vh + (size_t)kr1 * T_SEQ + gc1 * 8;
  int woff = wave * 512; // wave-uniform LDS dest (elems); lane -> +lane*8

  auto stage = [&](int buf, int kbase) {
    gl2lds16(kg0 + (size_t)kbase * D_MODEL, kT[buf] + woff);
    gl2lds16(kg1 + (size_t)kbase * D_MODEL, kT[buf] + 2048 + woff);
    gl2lds16(vg0 + kbase, vT[buf] + woff);
    gl2lds16(vg1 + kbase, vT[buf] + 2048 + woff);
  };

  stage(0, 0);
  __syncthreads();

  for (int kt = 0; kt < T_SEQ / 64; kt++) {
    int kbase = kt * 64;
    int buf = kt & 1;
    if (kt + 1 < T_SEQ / 64) stage(buf ^ 1, kbase + 64);
    const u16* kb = kT[buf];
    const u16* vb = vT[buf];

    // K A-frags: row k = nt*16+l15
    bf8v kf0[4], kf1[4];
#pragma unroll
    for (int nt = 0; nt < 4; nt++) {
      kf0[nt] = *(const bf8v*)(kb + kidx[nt]);
      kf1[nt] = *(const bf8v*)(kb + (kidx[nt] ^ 32));
    }
    // V B-frags: row d = dt*16+l15; key-chunks gc = kc*4+quad
    bf8v vf[2][4];
#pragma unroll
    for (int dt = 0; dt < 4; dt++) {
      vf[0][dt] = *(const bf8v*)(vb + vidx[dt]);
      vf[1][dt] = *(const bf8v*)(vb + (vidx[dt] ^ 32));
    }
    // bias precompute (header, packed-math friendly): m = (fk - fq)*sel
    f32x4 bias2[2][4];
#pragma unroll
    for (int nt = 0; nt < 4; nt++) {
      f32x4 fk = *(const f32x4*)(fb + kbase + nt * 16 + quad * 4);
#pragma unroll
      for (int g = 0; g < 2; g++) {
        f32x4 dd = fk - fq[g];
        f32x4 m;
#pragma unroll
        for (int r = 0; r < 4; r++) m[r] = dd[r] * ((dd[r] >= 0.0f) ? ap : an);
        bias2[g][nt] = m;
      }
    }

    // S^T + exp + P-write for BOTH g, then one drain.
#pragma unroll
    for (int g = 0; g < 2; g++) {
      u16* pwg = pw + g * (16 * 72);
#pragma unroll
      for (int nt = 0; nt < 4; nt++) {
        // S^T tile: D[row=key=nt*16+quad*4+r][col=q=l15], log2 domain
        f32x4 s = {};
        s = __builtin_amdgcn_mfma_f32_16x16x32_bf16(kf0[nt], qf[g][0], s, 0, 0, 0);
        s = __builtin_amdgcn_mfma_f32_16x16x32_bf16(kf1[nt], qf[g][1], s, 0, 0, 0);
        bf4v pk;
#pragma unroll
        for (int r = 0; r < 4; r++)
          pk[r] = (__bf16)__builtin_amdgcn_exp2f(s[r] + bias2[g][nt][r]);
        // P[q=l15][key = nt*16 + quad*4 + r] -> one b64 write
        *(bf4v*)(pwg + l15 * 72 + nt * 16 + quad * 4) = pk;
      }
    }
    asm volatile("s_waitcnt lgkmcnt(0)" ::: "memory"); // P visible to own wave

    // O += P @ V ; l += P @ ones  (A = P: lane holds P[q=l15][k=kc*32+quad*8+j])
#pragma unroll
    for (int g = 0; g < 2; g++) {
      const u16* pwg = pw + g * (16 * 72);
#pragma unroll
      for (int kc = 0; kc < 2; kc++) {
        bf8v pf = *(const bf8v*)(pwg + pidx + kc * 32);
        o_l[g] = __builtin_amdgcn_mfma_f32_16x16x32_bf16(pf, onesv, o_l[g], 0, 0, 0);
#pragma unroll
        for (int dt = 0; dt < 4; dt++)
          o[g][dt] = __builtin_amdgcn_mfma_f32_16x16x32_bf16(pf, vf[kc][dt],
                                                             o[g][dt], 0, 0, 0);
      }
    }
    __syncthreads(); // drains this iter's DMA (vmcnt) + frees cur buf
  }

  // epilogue: l sits in o_l C-layout rows (same rows as o)
#pragma unroll
  for (int g = 0; g < 2; g++) {
#pragma unroll
    for (int r = 0; r < 4; r++) {
      float linv = 1.0f / o_l[g][r];
      int qg = q0 + wave * 32 + g * 16 + quad * 4 + r;
      __bf16* orow = (__bf16*)(ctx + (size_t)(b * T_SEQ + qg) * D_MODEL + h * HDIM);
#pragma unroll
      for (int dt = 0; dt < 4; dt++)
        orow[dt * 16 + l15] = (__bf16)(o[g][dt][r] * linv);
    }
  }
}

// ---------------------------------------------------------------------------
extern "C" void kernel_launch(void* const* d_in, const int* in_sizes, int n_in,
                              void* d_out, int out_size, void* d_ws,
                              size_t ws_size, hipStream_t stream) {
  const float* q = (const float*)d_in[0];
  const float* k = (const float*)d_in[1];
  const float* v = (const float*)d_in[2];
  const float* frac = (const float*)d_in[3];
  const float* Wq = (const float*)d_in[4];
  const float* Wk = (const float*)d_in[5];
  const float* Wv = (const float*)d_in[6];
  const float* Wo = (const float*)d_in[7];
  const float* bq = (const float*)d_in[8];
  const float* bk = (const float*)d_in[9];
  const float* bv = (const float*)d_in[10];
  const float* bo = (const float*)d_in[11];
  const float* alpha_pos = (const float*)d_in[12];
  const float* alpha_neg = (const float*)d_in[13];

  char* ws = (char*)d_ws;
  u16* Xb = (u16*)(ws + 0);
  u16* Wt = (u16*)(ws + 25165824);
  u16* Qr = (u16*)(ws + 33554432);
  u16* Kr = (u16*)(ws + 41943040);
  u16* Vtmp = (u16*)(ws + 50331648); // holds ctx
  u16* Vb = (u16*)(ws + 58720256);
  float* ctab = (float*)(ws + 67108864);
  float* stab = (float*)(ws + 67371008);
  u16* ctx = Vtmp;
  u16* QKVout = Qr; // Qr,Kr contiguous; z==2 writes Vb directly

  k_prep<<<dim3(7424), 256, 0, stream>>>(q, k, v, Wq, Wk, Wv, Wo, Xb, Wt, ctab,
                                         stab);
  k_gemm_qkv<<<dim3(8, 32, 3), 256, 0, stream>>>(Xb, Wt, bq, bk, bv, ctab, stab,
                                                 QKVout, Vb);
  k_attn<<<dim3(16, 32), 256, 0, stream>>>(Qr, Kr, Vb, frac, alpha_pos,
                                           alpha_neg, ctx);
  k_gemm_out<<<dim3(16, 32), 256, 0, stream>>>(ctx, Wt + 3 * 1048576, bo,
                                               (float*)d_out);
}

// Round 7
// 256.680 us; speedup vs baseline: 1.0718x; 1.0007x over previous
//
#include <hip/hip_runtime.h>

// ---------------------------------------------------------------------------
// CustomMultiHeadAttentionStoich: fused MHA with RoPE + frac-difference bias.
// B=2 T=2048 D_MODEL=1024 H=16 hd=64. All matmuls via mfma_f32_16x16x32_bf16.
//
// Verified gfx950 fragment layouts (learn_hip m89/m91, rounds 1-6 pass):
//   A-frag : lane holds A[m=lane&15][k=(lane>>4)*8 + j], j=0..7  (8 bf16, 16B)
//   B-frag : lane holds B[k=(lane>>4)*8 + j][n=lane&15]
//   C/D    : lane holds D[row=(lane>>4)*4 + r][col=lane&15], r=0..3 (4 f32)
//
// Round-7 changes:
//  * k_attn: r5's per-g drain structure (VGPR 92; r6's merged drain raised
//    VGPR to 124 and regressed) + r6's hoisted LDS frag offsets.
//  * k_gemm_out: 64x64 tiles, grid (16,64)=1024 blocks = 4 blocks/CU
//    (LDS 16 KB) -- barrier drains of one block overlap compute of the
//    other three. Wave-tile 32x32, plane-structured BK=64 staging.
//  * k_prep / k_gemm_qkv unchanged from r6 (BK=64 2-barrier, fused RoPE /
//    V-transpose epilogues).
// ---------------------------------------------------------------------------

typedef unsigned short u16;
typedef __bf16 bf8v __attribute__((ext_vector_type(8)));
typedef __bf16 bf4v __attribute__((ext_vector_type(4)));
typedef float f32x4 __attribute__((ext_vector_type(4)));

#define D_MODEL 1024
#define T_SEQ   2048
#define NHEAD   16
#define HDIM    64
#define BATCH   2
#define M_TOT   (BATCH * T_SEQ) /* 4096 */
#define LOG2E   1.4426950408889634f

__device__ __forceinline__ void gl2lds16(const u16* g, u16* l) {
  __builtin_amdgcn_global_load_lds(
      (__attribute__((address_space(1))) void*)g,
      (__attribute__((address_space(3))) void*)l, 16, 0, 0);
}

// ---------------------------------------------------------------------------
// k_prep: zone-partitioned prep work in ONE launch.
//   blocks [0,6144)    : f32->bf16 convert of q/k/v into Xb
//   blocks [6144,7168) : W^T bf16 transpose of Wq/Wk/Wv/Wo into WtB
//   blocks [7168,7424) : RoPE cos/sin table
__global__ __launch_bounds__(256) void k_prep(
    const float* __restrict__ q, const float* __restrict__ k,
    const float* __restrict__ v, const float* __restrict__ Wq,
    const float* __restrict__ Wk, const float* __restrict__ Wv,
    const float* __restrict__ Wo, u16* __restrict__ Xb, u16* __restrict__ WtB,
    float* __restrict__ ct, float* __restrict__ st) {
  __shared__ float tile[64 * 65];
  int bx = blockIdx.x, tid = threadIdx.x;
  if (bx < 6144) { // ---- convert zone
    int z = bx >> 11, xb = bx & 2047;
    const float* src = (z == 0) ? q : (z == 1) ? k : v;
    u16* dst = Xb + (size_t)z * (M_TOT * D_MODEL);
    int idx = (xb * 256 + tid) * 8;
    float4 a = *(const float4*)(src + idx);
    float4 b = *(const float4*)(src + idx + 4);
    bf8v o;
    o[0] = (__bf16)a.x; o[1] = (__bf16)a.y; o[2] = (__bf16)a.z; o[3] = (__bf16)a.w;
    o[4] = (__bf16)b.x; o[5] = (__bf16)b.y; o[6] = (__bf16)b.z; o[7] = (__bf16)b.w;
    *(bf8v*)(dst + idx) = o;
  } else if (bx < 7168) { // ---- W transpose zone (64x64 tiles, stride 65)
    int idx2 = bx - 6144;
    int z = idx2 >> 8, rem = idx2 & 255;
    int k0 = (rem >> 4) * 64, n0 = (rem & 15) * 64;
    const float* W = (z == 0) ? Wq : (z == 1) ? Wk : (z == 2) ? Wv : Wo;
    u16* Wt = WtB + (size_t)z * (D_MODEL * D_MODEL);
#pragma unroll
    for (int i = 0; i < 16; i++) {
      int idx = tid + i * 256;
      int r = idx >> 6, c = idx & 63;
      tile[c * 65 + r] = W[(size_t)(k0 + r) * D_MODEL + n0 + c];
    }
    __syncthreads();
#pragma unroll
    for (int i = 0; i < 16; i++) {
      int idx = tid + i * 256;
      int r = idx >> 6, c = idx & 63;
      ((__bf16*)Wt)[(size_t)(n0 + r) * D_MODEL + k0 + c] = (__bf16)tile[r * 65 + c];
    }
  } else { // ---- RoPE table zone: angle(t,d) = t / 10000^(d/32)
    int idx = (bx - 7168) * 256 + tid; // = t*32 + d
    int t = idx >> 5, d = idx & 31;
    float ang = (float)t * powf(10000.0f, -(float)d * (1.0f / 32.0f));
    ct[idx] = cosf(ang);
    st[idx] = sinf(ang);
  }
}

// ---------------------------------------------------------------------------
// QKV GEMM core (r4/r6 structure): C = A[M][K] @ Bt[N][K]^T, K=1024, BK=64
// (two stride-32 planes per operand, bank-balanced b128 frag reads).
// 2-barrier single-buffer global_load_lds staging. BM=128, BN=128.
__device__ __forceinline__ void gemm_core_128(const u16* __restrict__ A,
                                              const u16* __restrict__ Bt,
                                              u16* sA, u16* sB,
                                              f32x4 (&acc)[4][4],
                                              int m0, int n0) {
  const int K = D_MODEL;
  int tid = threadIdx.x;
  int lane = tid & 63, wave = tid >> 6;
  int l15 = lane & 15, quad = lane >> 4;
  int wm = (wave >> 1) * 64, wn = (wave & 1) * 64;
  int r0 = tid >> 2, pcol0 = (tid & 3) * 8;
  int r1 = 64 + r0;
  const u16* A0 = A + (size_t)(m0 + r0) * K + pcol0;
  const u16* A1 = A + (size_t)(m0 + r1) * K + pcol0;
  const u16* B0 = Bt + (size_t)(n0 + r0) * K + pcol0;
  const u16* B1 = Bt + (size_t)(n0 + r1) * K + pcol0;
  u16* dA0 = sA + wave * 512;        // plane0, rows 0..63 (wave-uniform base)
  u16* dA1 = sA + 2048 + wave * 512; // plane0, rows 64..127
  u16* dB0 = sB + wave * 512;
  u16* dB1 = sB + 2048 + wave * 512;
  for (int k0 = 0; k0 < K; k0 += 64) {
    __syncthreads(); // previous iter's frag reads done
    gl2lds16(A0 + k0, dA0);
    gl2lds16(A1 + k0, dA1);
    gl2lds16(A0 + k0 + 32, dA0 + 4096); // plane1
    gl2lds16(A1 + k0 + 32, dA1 + 4096);
    gl2lds16(B0 + k0, dB0);
    gl2lds16(B0 + k0 + 32, dB0 + 4096);
    gl2lds16(B1 + k0, dB1);
    gl2lds16(B1 + k0 + 32, dB1 + 4096);
    __syncthreads(); // barrier drain -> LDS data visible
#pragma unroll
    for (int kh = 0; kh < 2; kh++) {
      bf8v af[4], bf[4];
#pragma unroll
      for (int i = 0; i < 4; i++)
        af[i] = *(const bf8v*)(sA + kh * 4096 + (wm + i * 16 + l15) * 32 + quad * 8);
#pragma unroll
      for (int i = 0; i < 4; i++)
        bf[i] = *(const bf8v*)(sB + kh * 4096 + (wn + i * 16 + l15) * 32 + quad * 8);
#pragma unroll
      for (int mi = 0; mi < 4; mi++)
#pragma unroll
        for (int ni = 0; ni < 4; ni++)
          acc[mi][ni] = __builtin_amdgcn_mfma_f32_16x16x32_bf16(
              af[mi], bf[ni], acc[mi][ni], 0, 0, 0);
    }
  }
}

// QKV projection, grid (8, 32, 3). z<2 -> RoPE fused; z==0 prescales Q by
// 0.125*log2e. z==2 writes projected V DIRECTLY TRANSPOSED into Vb[b][h][d][t].
__global__ __launch_bounds__(256) void k_gemm_qkv(
    const u16* __restrict__ Xb, const u16* __restrict__ WtB,
    const float* __restrict__ bq, const float* __restrict__ bk,
    const float* __restrict__ bv, const float* __restrict__ ctab,
    const float* __restrict__ stab, u16* __restrict__ OutB,
    u16* __restrict__ Vb) {
  __shared__ __align__(16) u16 sA[128 * 64];
  __shared__ __align__(16) u16 sB[128 * 64];
  int z = blockIdx.z;
  const u16* A = Xb + (size_t)z * (M_TOT * D_MODEL);
  const u16* Bt = WtB + (size_t)z * (D_MODEL * D_MODEL);
  const float* bias = (z == 0) ? bq : (z == 1) ? bk : bv;
  u16* Out = OutB + (size_t)z * (M_TOT * D_MODEL);
  int m0 = blockIdx.y * 128, n0 = blockIdx.x * 128;
  f32x4 acc[4][4] = {};
  gemm_core_128(A, Bt, sA, sB, acc, m0, n0);

  int tid = threadIdx.x, lane = tid & 63, wave = tid >> 6;
  int l15 = lane & 15, quad = lane >> 4;
  int wm = (wave >> 1) * 64, wn = (wave & 1) * 64;
  float bvv[4];
#pragma unroll
  for (int ni = 0; ni < 4; ni++) bvv[ni] = bias[n0 + wn + ni * 16 + l15];

  if (z < 2) { // Q/K: RoPE fused; Q also prescaled 0.125*log2e
    float qs = (z == 0) ? 0.125f * LOG2E : 1.0f;
#pragma unroll
    for (int mi = 0; mi < 4; mi++) {
#pragma unroll
      for (int r = 0; r < 4; r++) {
        int m = m0 + wm + mi * 16 + quad * 4 + r; // global row = b*T + t
        size_t ro = (size_t)m * D_MODEL + n0 + wn;
        int tl = m & (T_SEQ - 1);
#pragma unroll
        for (int ni = 0; ni < 2; ni++) {
          int d = ni * 16 + l15; // < 32; pair (d, d+32) in regs ni, ni+2
          float c = ctab[tl * 32 + d], s = stab[tl * 32 + d];
          float xl = acc[mi][ni][r] + bvv[ni];
          float xr = acc[mi][ni + 2][r] + bvv[ni + 2];
          ((__bf16*)Out)[ro + d] = (__bf16)((xl * c - xr * s) * qs);
          ((__bf16*)Out)[ro + d + 32] = (__bf16)((xl * s + xr * c) * qs);
        }
      }
    }
  } else { // V: write transposed Vb[b][h][d][t] (wave's 64 cols = one head)
    int hh = (n0 + wn) >> 6;
    int mbase = m0 + wm;
    int bb = mbase >> 11; // tile never crosses batch (2048 % 128 == 0)
    int tbase = mbase & (T_SEQ - 1);
    u16* Vw = Vb + (size_t)(bb * NHEAD + hh) * HDIM * T_SEQ;
#pragma unroll
    for (int mi = 0; mi < 4; mi++)
#pragma unroll
      for (int r = 0; r < 4; r++) {
        int t = tbase + mi * 16 + quad * 4 + r;
#pragma unroll
        for (int ni = 0; ni < 4; ni++) {
          int d = ni * 16 + l15;
          ((__bf16*)Vw)[(size_t)d * T_SEQ + t] = (__bf16)(acc[mi][ni][r] + bvv[ni]);
        }
      }
  }
}

// Output projection: ctx bf16 @ Wo^T + bo -> f32 d_out. 64x64 tiles, grid
// (16, 64) = 1024 blocks = 4 blocks/CU (LDS 16 KB): four independent blocks
// per CU stagger barrier drains. Wave-tile 32x32, BK=64 plane staging.
__global__ __launch_bounds__(256) void k_gemm_out(
    const u16* __restrict__ ctx, const u16* __restrict__ Wot,
    const float* __restrict__ bo, float* __restrict__ Cout) {
  __shared__ __align__(16) u16 sA[64 * 64];
  __shared__ __align__(16) u16 sB[64 * 64];
  const int K = D_MODEL;
  int m0 = blockIdx.y * 64, n0 = blockIdx.x * 64;
  int tid = threadIdx.x, lane = tid & 63, wave = tid >> 6;
  int l15 = lane & 15, quad = lane >> 4;
  int wm = (wave >> 1) * 32, wn = (wave & 1) * 32;
  int r0 = tid >> 2, pcol0 = (tid & 3) * 8;
  const u16* A0 = ctx + (size_t)(m0 + r0) * K + pcol0;
  const u16* B0 = Wot + (size_t)(n0 + r0) * K + pcol0;
  u16* dA = sA + wave * 512; // one call = one full 64x32 plane (256 thr)
  u16* dB = sB + wave * 512;
  f32x4 acc[2][2] = {};
  for (int k0 = 0; k0 < K; k0 += 64) {
    __syncthreads(); // previous iter's frag reads done
    gl2lds16(A0 + k0, dA);
    gl2lds16(A0 + k0 + 32, dA + 2048); // plane1
    gl2lds16(B0 + k0, dB);
    gl2lds16(B0 + k0 + 32, dB + 2048);
    __syncthreads(); // barrier drain -> LDS data visible
#pragma unroll
    for (int kh = 0; kh < 2; kh++) {
      bf8v af[2], bf[2];
#pragma unroll
      for (int i = 0; i < 2; i++)
        af[i] = *(const bf8v*)(sA + kh * 2048 + (wm + i * 16 + l15) * 32 + quad * 8);
#pragma unroll
      for (int i = 0; i < 2; i++)
        bf[i] = *(const bf8v*)(sB + kh * 2048 + (wn + i * 16 + l15) * 32 + quad * 8);
#pragma unroll
      for (int mi = 0; mi < 2; mi++)
#pragma unroll
        for (int ni = 0; ni < 2; ni++)
          acc[mi][ni] = __builtin_amdgcn_mfma_f32_16x16x32_bf16(
              af[mi], bf[ni], acc[mi][ni], 0, 0, 0);
    }
  }
  float bvv[2];
#pragma unroll
  for (int ni = 0; ni < 2; ni++) bvv[ni] = bo[n0 + wn + ni * 16 + l15];
#pragma unroll
  for (int mi = 0; mi < 2; mi++)
#pragma unroll
    for (int r = 0; r < 4; r++) {
      size_t ro = (size_t)(m0 + wm + mi * 16 + quad * 4 + r) * D_MODEL + n0 + wn;
#pragma unroll
      for (int ni = 0; ni < 2; ni++)
        Cout[ro + ni * 16 + l15] = acc[mi][ni][r] + bvv[ni];
    }
}

// ---------------------------------------------------------------------------
// Flash attention v7 (= v5 structure + hoisted offsets): grid (T/128, B*H),
// 256 thr (4 waves x 32q). K/V double-buffered via global_load_lds DMA, ONE
// __syncthreads per tile. XOR-chunk swizzle (pc = gc ^ (row&7)). S^T = K@Q^T
// -> per-lane softmax, no max-subtraction, exp2-native. Per-g P round-trip
// (g1's score VALU issues under g0's PV MFMAs).
__global__ __launch_bounds__(256) void k_attn(
    const u16* __restrict__ Qr, const u16* __restrict__ Kr,
    const u16* __restrict__ Vb, const float* __restrict__ frac,
    const float* __restrict__ alpha_pos, const float* __restrict__ alpha_neg,
    u16* __restrict__ ctx) {
  __shared__ __align__(16) u16 kT[2][64 * 64]; // swizzled [key][d], no pad
  __shared__ __align__(16) u16 vT[2][64 * 64]; // swizzled [d][key], no pad
  __shared__ __align__(16) u16 pT[4][2][16 * 72]; // per-wave per-g [q][key]
  int bh = blockIdx.y, b = bh >> 4, h = bh & 15;
  int q0 = blockIdx.x * 128;
  int tid = threadIdx.x, wave = tid >> 6, lane = tid & 63;
  int l15 = lane & 15, quad = lane >> 4;

  const u16* Kh = Kr + (size_t)b * T_SEQ * D_MODEL + h * HDIM;
  const u16* Vh = Vb + (size_t)bh * HDIM * T_SEQ;
  const float* fb = frac + b * T_SEQ;

  // Q B-frags (B[k=d][n=q] = Q[q][d]): lane holds Q[q=l15][d=quad*8+j]
  bf8v qf[2][2];
  float fq[2];
#pragma unroll
  for (int g = 0; g < 2; g++) {
    int qrow = q0 + wave * 32 + g * 16 + l15;
    const u16* qbase =
        Qr + (size_t)(b * T_SEQ + qrow) * D_MODEL + h * HDIM + quad * 8;
    qf[g][0] = *(const bf8v*)qbase;
    qf[g][1] = *(const bf8v*)(qbase + 32);
    fq[g] = fb[qrow]; // S^T col = q = l15
  }
  float ap = alpha_pos[h] * LOG2E, an = alpha_neg[h] * LOG2E;
  bf8v onesv;
#pragma unroll
  for (int j = 0; j < 8; j++) onesv[j] = (__bf16)1.0f;
  f32x4 o[2][4] = {};
  f32x4 o_l[2] = {};
  u16* pw = &pT[wave][0][0];

  // Hoisted frag offsets (elems). Swizzle: row k, chunk gc -> pc = gc^(k&7).
  int x0 = (quad ^ (l15 & 7)) * 8; // pc offset for gc=quad; gc+4 -> ^32 elems
  int kidx[4], vidx[4];
#pragma unroll
  for (int nt = 0; nt < 4; nt++) kidx[nt] = ((nt * 16 + l15) << 6) + x0;
#pragma unroll
  for (int dt = 0; dt < 4; dt++) vidx[dt] = ((dt * 16 + l15) << 6) + x0;
  int pidx = l15 * 72 + quad * 8;

  // DMA staging map: physical chunk p = j*256 + wave*64 + lane;
  // row = p>>3, pc = p&7; fetch global chunk gc = pc ^ (row&7).
  int p0 = tid, p1 = 256 + tid;
  int kr0 = p0 >> 3, gc0 = (p0 & 7) ^ (kr0 & 7);
  int kr1 = p1 >> 3, gc1 = (p1 & 7) ^ (kr1 & 7);
  const u16* kg0 = Kh + (size_t)kr0 * D_MODEL + gc0 * 8;
  const u16* kg1 = Kh + (size_t)kr1 * D_MODEL + gc1 * 8;
  const u16* vg0 = Vh + (size_t)kr0 * T_SEQ + gc0 * 8; // row = d here
  const u16* vg1 = Vh + (size_t)kr1 * T_SEQ + gc1 * 8;
  int woff = wave * 512; // wave-uniform LDS dest (elems); lane -> +lane*8

  auto stage = [&](int buf, int kbase) {
    gl2lds16(kg0 + (size_t)kbase * D_MODEL, kT[buf] + woff);
    gl2lds16(kg1 + (size_t)kbase * D_MODEL, kT[buf] + 2048 + woff);
    gl2lds16(vg0 + kbase, vT[buf] + woff);
    gl2lds16(vg1 + kbase, vT[buf] + 2048 + woff);
  };

  stage(0, 0);
  __syncthreads();

  for (int kt = 0; kt < T_SEQ / 64; kt++) {
    int kbase = kt * 64;
    int buf = kt & 1;
    if (kt + 1 < T_SEQ / 64) stage(buf ^ 1, kbase + 64);
    const u16* kb = kT[buf];
    const u16* vb = vT[buf];

    // K A-frags: row k = nt*16+l15
    bf8v kf0[4], kf1[4];
#pragma unroll
    for (int nt = 0; nt < 4; nt++) {
      kf0[nt] = *(const bf8v*)(kb + kidx[nt]);
      kf1[nt] = *(const bf8v*)(kb + (kidx[nt] ^ 32));
    }
    // V B-frags: row d = dt*16+l15; key-chunks gc = kc*4+quad
    bf8v vf[2][4];
#pragma unroll
    for (int dt = 0; dt < 4; dt++) {
      vf[0][dt] = *(const bf8v*)(vb + vidx[dt]);
      vf[1][dt] = *(const bf8v*)(vb + (vidx[dt] ^ 32));
    }
    // frac[key] for this lane's 4 keys per nt (L1-resident)
    f32x4 fk4[4];
#pragma unroll
    for (int nt = 0; nt < 4; nt++)
      fk4[nt] = *(const f32x4*)(fb + kbase + nt * 16 + quad * 4);

#pragma unroll
    for (int g = 0; g < 2; g++) {
      float fqg = fq[g];
      u16* pwg = pw + g * (16 * 72);
#pragma unroll
      for (int nt = 0; nt < 4; nt++) {
        // S^T tile: D[row=key=nt*16+quad*4+r][col=q=l15], log2 domain
        f32x4 s = {};
        s = __builtin_amdgcn_mfma_f32_16x16x32_bf16(kf0[nt], qf[g][0], s, 0, 0, 0);
        s = __builtin_amdgcn_mfma_f32_16x16x32_bf16(kf1[nt], qf[g][1], s, 0, 0, 0);
        bf4v pk;
#pragma unroll
        for (int r = 0; r < 4; r++) {
          float dd = fk4[nt][r] - fqg;
          float sel = (dd >= 0.0f) ? ap : an;
          pk[r] = (__bf16)__builtin_amdgcn_exp2f(fmaf(dd, sel, s[r]));
        }
        // P[q=l15][key = nt*16 + quad*4 + r] -> one b64 write
        *(bf4v*)(pwg + l15 * 72 + nt * 16 + quad * 4) = pk;
      }
      asm volatile("s_waitcnt lgkmcnt(0)" ::: "memory"); // P visible to own wave
      // O_g += P_g @ V ; l_g += P_g @ ones. Drains while next g's score
      // VALU issues (separate pipes, same wave).
#pragma unroll
      for (int kc = 0; kc < 2; kc++) {
        bf8v pf = *(const bf8v*)(pwg + pidx + kc * 32);
        o_l[g] = __builtin_amdgcn_mfma_f32_16x16x32_bf16(pf, onesv, o_l[g], 0, 0, 0);
#pragma unroll
        for (int dt = 0; dt < 4; dt++)
          o[g][dt] = __builtin_amdgcn_mfma_f32_16x16x32_bf16(pf, vf[kc][dt],
                                                             o[g][dt], 0, 0, 0);
      }
    }
    __syncthreads(); // drains this iter's DMA (vmcnt) + frees cur buf
  }

  // epilogue: l sits in o_l C-layout rows (same rows as o)
#pragma unroll
  for (int g = 0; g < 2; g++) {
#pragma unroll
    for (int r = 0; r < 4; r++) {
      float linv = 1.0f / o_l[g][r];
      int qg = q0 + wave * 32 + g * 16 + quad * 4 + r;
      __bf16* orow = (__bf16*)(ctx + (size_t)(b * T_SEQ + qg) * D_MODEL + h * HDIM);
#pragma unroll
      for (int dt = 0; dt < 4; dt++)
        orow[dt * 16 + l15] = (__bf16)(o[g][dt][r] * linv);
    }
  }
}

// ---------------------------------------------------------------------------
extern "C" void kernel_launch(void* const* d_in, const int* in_sizes, int n_in,
                              void* d_out, int out_size, void* d_ws,
                              size_t ws_size, hipStream_t stream) {
  const float* q = (const float*)d_in[0];
  const float* k = (const float*)d_in[1];
  const float* v = (const float*)d_in[2];
  const float* frac = (const float*)d_in[3];
  const float* Wq = (const float*)d_in[4];
  const float* Wk = (const float*)d_in[5];
  const float* Wv = (const float*)d_in[6];
  const float* Wo = (const float*)d_in[7];
  const float* bq = (const float*)d_in[8];
  const float* bk = (const float*)d_in[9];
  const float* bv = (const float*)d_in[10];
  const float* bo = (const float*)d_in[11];
  const float* alpha_pos = (const float*)d_in[12];
  const float* alpha_neg = (const float*)d_in[13];

  char* ws = (char*)d_ws;
  u16* Xb = (u16*)(ws + 0);
  u16* Wt = (u16*)(ws + 25165824);
  u16* Qr = (u16*)(ws + 33554432);
  u16* Kr = (u16*)(ws + 41943040);
  u16* Vtmp = (u16*)(ws + 50331648); // holds ctx
  u16* Vb = (u16*)(ws + 58720256);
  float* ctab = (float*)(ws + 67108864);
  float* stab = (float*)(ws + 67371008);
  u16* ctx = Vtmp;
  u16* QKVout = Qr; // Qr,Kr contiguous; z==2 writes Vb directly

  k_prep<<<dim3(7424), 256, 0, stream>>>(q, k, v, Wq, Wk, Wv, Wo, Xb, Wt, ctab,
                                         stab);
  k_gemm_qkv<<<dim3(8, 32, 3), 256, 0, stream>>>(Xb, Wt, bq, bk, bv, ctab, stab,
                                                 QKVout, Vb);
  k_attn<<<dim3(16, 32), 256, 0, stream>>>(Qr, Kr, Vb, frac, alpha_pos,
                                           alpha_neg, ctx);
  k_gemm_out<<<dim3(16, 64), 256, 0, stream>>>(ctx, Wt + 3 * 1048576, bo,
                                               (float*)d_out);
}